// Round 3
// baseline (242.646 us; speedup 1.0000x reference)
//
#include <hip/hip_runtime.h>
#include <hip/hip_cooperative_groups.h>
#include <math.h>

namespace cg = cooperative_groups;

#define SRATE 48000
#define NN    480000
#define MAXD  50
#define TPB   256
#define NV4   (NN / 4)                     // 120000 float4 segments
#define GBLK  ((NV4 + TPB - 1) / TPB)      // 469 blocks (<=2/CU, coop-safe)
#define GTHR  (GBLK * TPB)                 // 120064 threads

__device__ __forceinline__ float clampf(float v, float lo, float hi) {
    return fminf(fmaxf(v, lo), hi);
}

struct Params { float al, bl, ah, bh, feedback, gain; int dl, nd; };

__device__ __forceinline__ Params load_params(const float* __restrict__ p) {
    Params q;
    float freq  = clampf(p[0], 20.0f, (float)(SRATE / 2));
    q.feedback  = clampf(p[1], 0.0f, 0.99f);
    float alow  = clampf(p[2], 1e-7f, 0.99f);
    float ahigh = clampf(p[3], 1e-7f, 0.99f);
    q.gain      = fmaxf(p[4], 1e-7f);
    float dlf   = clampf(floorf((float)SRATE / freq), 1.0f, (float)(NN / 2));
    q.dl = (int)dlf;
    q.nd = min(NN / q.dl, MAXD);
    q.al = alow;  q.bl = 1.0f - alow;
    q.ah = ahigh; q.bh = 1.0f - ahigh;
    return q;
}

// Thread-local affine over a float4 segment: state_out = Y + D*state_in.
__device__ __forceinline__ void seg_affine(const float4& v, float a, float b,
                                           float& Y, float& D) {
    float t = v.x;
    t = fmaf(t, b, v.y);
    t = fmaf(t, b, v.z);
    t = fmaf(t, b, v.w);
    Y = a * t;
    float b2 = b * b;
    D = b2 * b2;
}

// Wave-level inclusive scan of affine pairs (composition: later ∘ earlier).
__device__ __forceinline__ void wave_scan(int lane, float& Yl, float& Dl,
                                          float& Yh, float& Dh) {
    for (int off = 1; off < 64; off <<= 1) {
        float pYl = __shfl_up(Yl, off), pDl = __shfl_up(Dl, off);
        float pYh = __shfl_up(Yh, off), pDh = __shfl_up(Dh, off);
        if (lane >= off) {
            Yl = fmaf(Dl, pYl, Yl); Dl *= pDl;
            Yh = fmaf(Dh, pYh, Yh); Dh *= pDh;
        }
    }
}

__global__ __launch_bounds__(TPB) void resonator_fused(
    const float* __restrict__ input, const float* __restrict__ p,
    const float* __restrict__ x, float* __restrict__ filtered,
    float4* __restrict__ blkAgg, float* __restrict__ out)
{
    cg::grid_group grid = cg::this_grid();
    Params q = load_params(p);
    const int tid  = threadIdx.x;
    const int lane = tid & 63;
    const int wv   = tid >> 6;
    const int t    = blockIdx.x * TPB + tid;
    const bool valid = (t < NV4);

    // ======== Phase A: per-block affine aggregate ========
    float4 v = make_float4(0.f, 0.f, 0.f, 0.f);
    float Yl = 0.f, Dl = 1.f, Yh = 0.f, Dh = 1.f;
    if (valid) {
        v = ((const float4*)x)[t];
        seg_affine(v, q.al, q.bl, Yl, Dl);
        seg_affine(v, q.ah, q.bh, Yh, Dh);
    }
    wave_scan(lane, Yl, Dl, Yh, Dh);

    __shared__ float wYl[4], wDl[4], wYh[4], wDh[4];
    if (lane == 63) { wYl[wv] = Yl; wDl[wv] = Dl; wYh[wv] = Yh; wDh[wv] = Dh; }
    __syncthreads();
    if (tid == TPB - 1) {                 // lane 63 of wave 3 holds its inclusive
        float cYl = 0.f, cDl = 1.f, cYh = 0.f, cDh = 1.f;
        for (int j = 0; j < 3; ++j) {     // compose waves 0..2 in order
            cYl = fmaf(wDl[j], cYl, wYl[j]); cDl *= wDl[j];
            cYh = fmaf(wDh[j], cYh, wYh[j]); cDh *= wDh[j];
        }
        float AYl = fmaf(Dl, cYl, Yl), ADl = Dl * cDl;
        float AYh = fmaf(Dh, cYh, Yh), ADh = Dh * cDh;
        blkAgg[blockIdx.x] = make_float4(AYl, ADl, AYh, ADh);
    }
    __threadfence();
    grid.sync();

    // ======== Phase B: redundant block-carry scan + apply ========
    __shared__ float sYl[TPB], sDl[TPB], sYh[TPB], sDh[TPB];
    {
        int i2 = 2 * tid;                 // pair-compose 469 -> 256 entries
        float4 a0 = (i2     < GBLK) ? blkAgg[i2]     : make_float4(0.f, 1.f, 0.f, 1.f);
        float4 a1 = (i2 + 1 < GBLK) ? blkAgg[i2 + 1] : make_float4(0.f, 1.f, 0.f, 1.f);
        sYl[tid] = fmaf(a1.y, a0.x, a1.x); sDl[tid] = a1.y * a0.y;
        sYh[tid] = fmaf(a1.w, a0.z, a1.z); sDh[tid] = a1.w * a0.w;
    }
    __syncthreads();
    for (int off = 1; off < TPB; off <<= 1) {
        float cyl = sYl[tid], cdl = sDl[tid], cyh = sYh[tid], cdh = sDh[tid];
        float pyl = 0.f, pdl = 1.f, pyh = 0.f, pdh = 1.f;
        bool has = (tid >= off);
        if (has) { pyl = sYl[tid-off]; pdl = sDl[tid-off];
                   pyh = sYh[tid-off]; pdh = sDh[tid-off]; }
        __syncthreads();
        if (has) {
            sYl[tid] = fmaf(cdl, pyl, cyl); sDl[tid] = cdl * pdl;
            sYh[tid] = fmaf(cdh, pyh, cyh); sDh[tid] = cdh * pdh;
        }
        __syncthreads();
    }
    __shared__ float GYl_s, GYh_s;
    if (tid == 0) {
        int b = blockIdx.x;
        int qq = b >> 1;
        float GYl = 0.f, GDl = 1.f, GYh = 0.f, GDh = 1.f;
        if (qq > 0) { GYl = sYl[qq-1]; GDl = sDl[qq-1];
                      GYh = sYh[qq-1]; GDh = sDh[qq-1]; }
        if (b & 1) {                      // odd block: also fold in block 2q
            float4 am = blkAgg[2 * qq];
            GYl = fmaf(am.y, GYl, am.x); GDl = am.y * GDl;
            GYh = fmaf(am.w, GYh, am.z); GDh = am.w * GDh;
        }
        (void)GDl; (void)GDh;             // initial state is 0: only Y matters
        GYl_s = GYl; GYh_s = GYh;
    }
    __syncthreads();

    // per-thread entering state = (laneExcl ∘ waveCarry) applied to block carry
    float eYl = __shfl_up(Yl, 1), eDl = __shfl_up(Dl, 1);
    float eYh = __shfl_up(Yh, 1), eDh = __shfl_up(Dh, 1);
    if (lane == 0) { eYl = 0.f; eDl = 1.f; eYh = 0.f; eDh = 1.f; }
    float cYl = 0.f, cDl = 1.f, cYh = 0.f, cDh = 1.f;
    for (int j = 0; j < 3; ++j) {
        if (j < wv) {
            cYl = fmaf(wDl[j], cYl, wYl[j]); cDl *= wDl[j];
            cYh = fmaf(wDh[j], cYh, wYh[j]); cDh *= wDh[j];
        }
    }
    float BYl = fmaf(eDl, cYl, eYl), BDl = eDl * cDl;
    float BYh = fmaf(eDh, cYh, eYh), BDh = eDh * cDh;
    float yl = fmaf(BDl, GYl_s, BYl);
    float yh = fmaf(BDh, GYh_s, BYh);

    if (valid) {
        float4 o;
        yl = fmaf(q.bl, yl, q.al * v.x); yh = fmaf(q.bh, yh, q.ah * v.x); o.x = yh - yl;
        yl = fmaf(q.bl, yl, q.al * v.y); yh = fmaf(q.bh, yh, q.ah * v.y); o.y = yh - yl;
        yl = fmaf(q.bl, yl, q.al * v.z); yh = fmaf(q.bh, yh, q.ah * v.z); o.z = yh - yl;
        yl = fmaf(q.bl, yl, q.al * v.w); yh = fmaf(q.bh, yh, q.ah * v.w); o.w = yh - yl;
        ((float4*)filtered)[t] = o;
    }
    __threadfence();
    grid.sync();

    // ======== Phase C: taps + tanh (grid-stride x4, 4-way MLP) ========
    const int g  = blockIdx.x * TPB + tid;
    const int n0 = g;
    const int n1 = g + GTHR;
    const int n2 = g + 2 * GTHR;
    const int n3 = g + 3 * GTHR;          // may exceed NN (guarded)
    float acc0 = input[n0];
    float acc1 = input[n1];
    float acc2 = input[n2];
    float acc3 = (n3 < NN) ? input[n3] : 0.f;
    int s = q.dl;
    float wgt = q.feedback;
    for (int i = 1; i < q.nd; ++i) {
        int a0 = n0 - s, a1 = n1 - s, a2 = n2 - s, a3 = n3 - s;
        float f0 = (a0 >= 0) ? filtered[a0] : 0.f;
        float f1 = (a1 >= 0) ? filtered[a1] : 0.f;
        float f2 = (a2 >= 0) ? filtered[a2] : 0.f;
        float f3 = (a3 >= 0 && n3 < NN) ? filtered[a3] : 0.f;
        acc0 = fmaf(wgt, f0, acc0);
        acc1 = fmaf(wgt, f1, acc1);
        acc2 = fmaf(wgt, f2, acc2);
        acc3 = fmaf(wgt, f3, acc3);
        s += q.dl;
        wgt *= q.feedback;
    }
    out[n0] = tanhf(acc0 * q.gain);
    out[n1] = tanhf(acc1 * q.gain);
    out[n2] = tanhf(acc2 * q.gain);
    if (n3 < NN) out[n3] = tanhf(acc3 * q.gain);
}

extern "C" void kernel_launch(void* const* d_in, const int* in_sizes, int n_in,
                              void* d_out, int out_size, void* d_ws, size_t ws_size,
                              hipStream_t stream)
{
    const float* input  = (const float*)d_in[0];
    const float* params = (const float*)d_in[1];
    const float* dbuf   = (const float*)d_in[2];
    float* out = (float*)d_out;

    float* ws       = (float*)d_ws;
    float* filtered = ws;                         // NN floats (16B-aligned)
    float4* blkAgg  = (float4*)(ws + NN);         // GBLK float4s

    void* args[] = { (void*)&input, (void*)&params, (void*)&dbuf,
                     (void*)&filtered, (void*)&blkAgg, (void*)&out };
    (void)hipLaunchCooperativeKernel((void*)resonator_fused, dim3(GBLK), dim3(TPB),
                                     args, 0, stream);
}

// Round 4
// 75.110 us; speedup vs baseline: 3.2305x; 3.2305x over previous
//
#include <hip/hip_runtime.h>
#include <math.h>

#define SRATE 48000
#define NN    480000
#define MAXD  50
#define TPB   256
#define NV4   (NN / 4)                     // 120000 float4 segments
#define NBLKS ((NV4 + TPB - 1) / TPB)      // 469 scan blocks / taps blocks

__device__ __forceinline__ float clampf(float v, float lo, float hi) {
    return fminf(fmaxf(v, lo), hi);
}

struct Params { float al, bl, ah, bh, feedback, gain; int dl, nd; };

__device__ __forceinline__ Params load_params(const float* __restrict__ p) {
    Params q;
    float freq  = clampf(p[0], 20.0f, (float)(SRATE / 2));
    q.feedback  = clampf(p[1], 0.0f, 0.99f);
    float alow  = clampf(p[2], 1e-7f, 0.99f);
    float ahigh = clampf(p[3], 1e-7f, 0.99f);
    q.gain      = fmaxf(p[4], 1e-7f);
    float dlf   = clampf(floorf((float)SRATE / freq), 1.0f, (float)(NN / 2));
    q.dl = (int)dlf;
    q.nd = min(NN / q.dl, MAXD);
    q.al = alow;  q.bl = 1.0f - alow;
    q.ah = ahigh; q.bh = 1.0f - ahigh;
    return q;
}

// Thread-local affine over a float4 segment: state_out = Y + D*state_in.
__device__ __forceinline__ void seg_affine(const float4& v, float a, float b,
                                           float& Y, float& D) {
    float t = v.x;
    t = fmaf(t, b, v.y);
    t = fmaf(t, b, v.z);
    t = fmaf(t, b, v.w);
    Y = a * t;
    float b2 = b * b;
    D = b2 * b2;
}

// Wave-level inclusive scan of affine pairs (composition: later ∘ earlier).
__device__ __forceinline__ void wave_scan(int lane, float& Yl, float& Dl,
                                          float& Yh, float& Dh) {
    for (int off = 1; off < 64; off <<= 1) {
        float pYl = __shfl_up(Yl, off), pDl = __shfl_up(Dl, off);
        float pYh = __shfl_up(Yh, off), pDh = __shfl_up(Dh, off);
        if (lane >= off) {
            Yl = fmaf(Dl, pYl, Yl); Dl *= pDl;
            Yh = fmaf(Dh, pYh, Yh); Dh *= pDh;
        }
    }
}

// Kernel A: per-block affine aggregate (both filters) -> blkAgg[b] = (Yl,Dl,Yh,Dh)
__global__ __launch_bounds__(TPB) void scan_agg(
    const float* __restrict__ x, const float* __restrict__ p,
    float4* __restrict__ blkAgg)
{
    Params q = load_params(p);
    int tid = threadIdx.x;
    int t = blockIdx.x * TPB + tid;
    float Yl = 0.f, Dl = 1.f, Yh = 0.f, Dh = 1.f;
    if (t < NV4) {
        float4 v = ((const float4*)x)[t];
        seg_affine(v, q.al, q.bl, Yl, Dl);
        seg_affine(v, q.ah, q.bh, Yh, Dh);
    }
    int lane = tid & 63;
    wave_scan(lane, Yl, Dl, Yh, Dh);

    __shared__ float wYl[4], wDl[4], wYh[4], wDh[4];
    int w = tid >> 6;
    if (lane == 63) { wYl[w] = Yl; wDl[w] = Dl; wYh[w] = Yh; wDh[w] = Dh; }
    __syncthreads();
    if (tid == TPB - 1) {                 // lane 63 of wave 3 holds its inclusive
        float cYl = 0.f, cDl = 1.f, cYh = 0.f, cDh = 1.f;
        for (int j = 0; j < 3; ++j) {     // compose waves 0..2 in order
            cYl = fmaf(wDl[j], cYl, wYl[j]); cDl *= wDl[j];
            cYh = fmaf(wDh[j], cYh, wYh[j]); cDh *= wDh[j];
        }
        float AYl = fmaf(Dl, cYl, Yl), ADl = Dl * cDl;
        float AYh = fmaf(Dh, cYh, Yh), ADh = Dh * cDh;
        blkAgg[blockIdx.x] = make_float4(AYl, ADl, AYh, ADh);
    }
}

// Kernel B: redundant block-carry scan + local re-scan + apply, write filtered.
__global__ __launch_bounds__(TPB) void scan_apply(
    const float* __restrict__ x, const float* __restrict__ p,
    const float4* __restrict__ blkAgg,
    float* __restrict__ filtered)
{
    Params q = load_params(p);
    int tid = threadIdx.x;
    int lane = tid & 63;
    int w = tid >> 6;
    int t = blockIdx.x * TPB + tid;
    bool valid = (t < NV4);

    float4 v = make_float4(0.f, 0.f, 0.f, 0.f);
    float Yl = 0.f, Dl = 1.f, Yh = 0.f, Dh = 1.f;
    if (valid) {
        v = ((const float4*)x)[t];
        seg_affine(v, q.al, q.bl, Yl, Dl);
        seg_affine(v, q.ah, q.bh, Yh, Dh);
    }
    wave_scan(lane, Yl, Dl, Yh, Dh);

    __shared__ float wYl[4], wDl[4], wYh[4], wDh[4];
    if (lane == 63) { wYl[w] = Yl; wDl[w] = Dl; wYh[w] = Yh; wDh[w] = Dh; }

    // ---- block-carry: scan 469 aggregates (pair-compose + Hillis-Steele) ----
    __shared__ float sYl[TPB], sDl[TPB], sYh[TPB], sDh[TPB];
    {
        int i2 = 2 * tid;
        float4 a0 = (i2     < NBLKS) ? blkAgg[i2]     : make_float4(0.f, 1.f, 0.f, 1.f);
        float4 a1 = (i2 + 1 < NBLKS) ? blkAgg[i2 + 1] : make_float4(0.f, 1.f, 0.f, 1.f);
        sYl[tid] = fmaf(a1.y, a0.x, a1.x); sDl[tid] = a1.y * a0.y;
        sYh[tid] = fmaf(a1.w, a0.z, a1.z); sDh[tid] = a1.w * a0.w;
    }
    __syncthreads();
    for (int off = 1; off < TPB; off <<= 1) {
        float cyl = sYl[tid], cdl = sDl[tid], cyh = sYh[tid], cdh = sDh[tid];
        float pyl = 0.f, pdl = 1.f, pyh = 0.f, pdh = 1.f;
        bool has = (tid >= off);
        if (has) { pyl = sYl[tid-off]; pdl = sDl[tid-off];
                   pyh = sYh[tid-off]; pdh = sDh[tid-off]; }
        __syncthreads();
        if (has) {
            sYl[tid] = fmaf(cdl, pyl, cyl); sDl[tid] = cdl * pdl;
            sYh[tid] = fmaf(cdh, pyh, cyh); sDh[tid] = cdh * pdh;
        }
        __syncthreads();
    }
    __shared__ float GYl_s, GYh_s;
    if (tid == 0) {
        int b = blockIdx.x;
        int qq = b >> 1;
        float GYl = 0.f, GDl = 1.f, GYh = 0.f, GDh = 1.f;
        if (qq > 0) { GYl = sYl[qq-1]; GDl = sDl[qq-1];
                      GYh = sYh[qq-1]; GDh = sDh[qq-1]; }
        if (b & 1) {                      // odd block: also fold in block 2q
            float4 am = blkAgg[2 * qq];
            GYl = fmaf(am.y, GYl, am.x); GDl = am.y * GDl;
            GYh = fmaf(am.w, GYh, am.z); GDh = am.w * GDh;
        }
        (void)GDl; (void)GDh;             // initial state is 0: only Y matters
        GYl_s = GYl; GYh_s = GYh;
    }
    __syncthreads();

    // per-thread entering state = (laneExcl ∘ waveCarry) applied to block carry
    float eYl = __shfl_up(Yl, 1), eDl = __shfl_up(Dl, 1);
    float eYh = __shfl_up(Yh, 1), eDh = __shfl_up(Dh, 1);
    if (lane == 0) { eYl = 0.f; eDl = 1.f; eYh = 0.f; eDh = 1.f; }
    float cYl = 0.f, cDl = 1.f, cYh = 0.f, cDh = 1.f;
    for (int j = 0; j < 3; ++j) {
        if (j < w) {
            cYl = fmaf(wDl[j], cYl, wYl[j]); cDl *= wDl[j];
            cYh = fmaf(wDh[j], cYh, wYh[j]); cDh *= wDh[j];
        }
    }
    float BYl = fmaf(eDl, cYl, eYl), BDl = eDl * cDl;
    float BYh = fmaf(eDh, cYh, eYh), BDh = eDh * cDh;
    float yl = fmaf(BDl, GYl_s, BYl);
    float yh = fmaf(BDh, GYh_s, BYh);

    if (valid) {
        float4 o;
        yl = fmaf(q.bl, yl, q.al * v.x); yh = fmaf(q.bh, yh, q.ah * v.x); o.x = yh - yl;
        yl = fmaf(q.bl, yl, q.al * v.y); yh = fmaf(q.bh, yh, q.ah * v.y); o.y = yh - yl;
        yl = fmaf(q.bl, yl, q.al * v.z); yh = fmaf(q.bh, yh, q.ah * v.z); o.z = yh - yl;
        yl = fmaf(q.bl, yl, q.al * v.w); yh = fmaf(q.bh, yh, q.ah * v.w); o.w = yh - yl;
        ((float4*)filtered)[t] = o;
    }
}

// Kernel C: taps + tanh. 4 consecutive outputs per thread. When dl%4==0
// (D=2400 here) tap validity and float4 alignment are uniform across the 4
// lanes: one vector load + 4 FMAs per tap. Scalar fallback otherwise.
__global__ __launch_bounds__(TPB) void taps_kernel(
    const float* __restrict__ input, const float* __restrict__ p,
    const float* __restrict__ filtered, float* __restrict__ out)
{
    int t = blockIdx.x * TPB + threadIdx.x;
    if (t >= NV4) return;
    Params q = load_params(p);
    int n0 = t * 4;
    float4 in4 = ((const float4*)input)[t];
    float a0 = in4.x, a1 = in4.y, a2 = in4.z, a3 = in4.w;

    if ((q.dl & 3) == 0) {
        int m = min(q.nd - 1, n0 / q.dl);     // taps valid for all 4 lanes
        int s = q.dl;
        float wgt = q.feedback;
        for (int i = 1; i <= m; ++i) {
            float4 f = *(const float4*)(filtered + (n0 - s));
            a0 = fmaf(wgt, f.x, a0);
            a1 = fmaf(wgt, f.y, a1);
            a2 = fmaf(wgt, f.z, a2);
            a3 = fmaf(wgt, f.w, a3);
            s += q.dl;
            wgt *= q.feedback;
        }
    } else {
        int s = q.dl;
        float wgt = q.feedback;
        for (int i = 1; i < q.nd; ++i) {
            if (s > n0 + 3) break;
            int b0 = n0 - s, b1 = b0 + 1, b2 = b0 + 2, b3 = b0 + 3;
            float f0 = (b0 >= 0) ? filtered[b0] : 0.f;
            float f1 = (b1 >= 0) ? filtered[b1] : 0.f;
            float f2 = (b2 >= 0) ? filtered[b2] : 0.f;
            float f3 = (b3 >= 0) ? filtered[b3] : 0.f;
            a0 = fmaf(wgt, f0, a0);
            a1 = fmaf(wgt, f1, a1);
            a2 = fmaf(wgt, f2, a2);
            a3 = fmaf(wgt, f3, a3);
            s += q.dl;
            wgt *= q.feedback;
        }
    }
    float4 o;
    o.x = tanhf(a0 * q.gain);
    o.y = tanhf(a1 * q.gain);
    o.z = tanhf(a2 * q.gain);
    o.w = tanhf(a3 * q.gain);
    ((float4*)out)[t] = o;
}

extern "C" void kernel_launch(void* const* d_in, const int* in_sizes, int n_in,
                              void* d_out, int out_size, void* d_ws, size_t ws_size,
                              hipStream_t stream)
{
    const float* input  = (const float*)d_in[0];
    const float* params = (const float*)d_in[1];
    const float* dbuf   = (const float*)d_in[2];
    float* out = (float*)d_out;

    float* ws       = (float*)d_ws;
    float* filtered = ws;                         // NN floats (16B-aligned)
    float4* blkAgg  = (float4*)(ws + NN);         // NBLKS float4s

    scan_agg  <<<NBLKS, TPB, 0, stream>>>(dbuf, params, blkAgg);
    scan_apply<<<NBLKS, TPB, 0, stream>>>(dbuf, params, blkAgg, filtered);
    taps_kernel<<<NBLKS, TPB, 0, stream>>>(input, params, filtered, out);
}